// Round 5
// baseline (176.358 us; speedup 1.0000x reference)
//
#include <hip/hip_runtime.h>
#include <hip/hip_bf16.h>
#include <hip/hip_fp16.h>

// EnhancedProxyNCALoss: B=4096, C=10000, D=128, SCALE=10, alpha=.25, gamma=2,
// k = int(9999*0.3) = 2999.
// Pipeline: prep (normalize+bf16 into ws, zero out) ->
//           bf16 MFMA gemm (64x128 tile) writing sim as 16-bit half-keys ->
//           per-row single-round 2048-bin select (2 global passes, no key LDS).

#define BATCH   4096
#define NCLASS  10000
#define EDIM    128
#define KSEL    2999
#define LDK     136
#define MLOG    10.0f   // sim <= 10 always (cosine * SCALE) -> safe softmax max

typedef __attribute__((ext_vector_type(8))) short short8;
typedef __attribute__((ext_vector_type(4))) float floatx4;

__device__ __forceinline__ unsigned short f2bf(float f) {
    unsigned int u = __float_as_uint(f);
    unsigned int r = (u + 0x7FFFu + ((u >> 16) & 1u)) >> 16;   // RNE
    return (unsigned short)r;
}
// float -> half (RNE) -> monotonic 16-bit key (order-preserving)
__device__ __forceinline__ unsigned int f2key16(float x) {
    unsigned short hb = __half_as_ushort(__float2half(x));
    return (hb & 0x8000u) ? (unsigned int)(~hb & 0xFFFFu)
                          : (unsigned int)(hb | 0x8000u);
}
__device__ __forceinline__ float key16val(unsigned int k) {
    unsigned short hb = (k & 0x8000u) ? (unsigned short)(k ^ 0x8000u)
                                      : (unsigned short)(~k & 0xFFFFu);
    return __half2float(__ushort_as_half(hb));
}

// ---------------------------------------------------------------- prep ------
__global__ __launch_bounds__(256) void prep_kernel(
    const float* __restrict__ emb, const float* __restrict__ px,
    unsigned short* __restrict__ px_bf, unsigned short* __restrict__ emb_bf,
    float* __restrict__ out)
{
    const int tid  = threadIdx.x;
    if (blockIdx.x == 0 && tid == 0) out[0] = 0.0f;
    const int lane = tid & 63;
    const int w    = tid >> 6;
    const int row  = blockIdx.x * 4 + w;   // grid = 3524 -> rows 0..14095

    const float* src;
    unsigned short* dst;
    float scale;
    if (row < NCLASS) {
        src = px + (size_t)row * EDIM;  dst = px_bf + (size_t)row * EDIM;  scale = 1.0f;
    } else {
        int r = row - NCLASS;
        src = emb + (size_t)r * EDIM;   dst = emb_bf + (size_t)r * EDIM;   scale = 10.0f;
    }
    float a = src[lane], b = src[lane + 64];
    float ss = a * a + b * b;
    #pragma unroll
    for (int off = 32; off; off >>= 1) ss += __shfl_xor(ss, off);
    float inv = scale / fmaxf(sqrtf(ss), 1e-12f);
    dst[lane]      = f2bf(a * inv);
    dst[lane + 64] = f2bf(b * inv);
}

// ---------------------------------------------------------------- gemm ------
// sim = emb10_hat . px_hat^T, bf16 MFMA 16x16x32, fp32 acc, 64x128 tile
// (A 17.4 KB + B 34.8 KB = 52.2 KB LDS -> 3 blocks/CU, was 2 at 128x128).
// Epilogue: fp32 -> half -> monotonic key16, LDS transpose (reuse Als),
// coalesced uint4 stores.
__global__ __launch_bounds__(256) void gemm_kernel(
    const unsigned short* __restrict__ emb_bf,
    const unsigned short* __restrict__ px_bf,
    unsigned short* __restrict__ simk, int row0)
{
    __shared__ __align__(16) unsigned short Als[64 * LDK];    // 17408 B
    __shared__ __align__(16) unsigned short Bls[128 * LDK];   // 34816 B

    const int tid  = threadIdx.x;
    const int lane = tid & 63;
    const int w    = tid >> 6;
    const int c0   = blockIdx.x * 128;
    const int rl0  = blockIdx.y * 64;
    const int rg0  = row0 + rl0;

    // stage A: 64 rows x 128 k = 1024 16B chunks, 4 per thread
    #pragma unroll
    for (int i = 0; i < 4; ++i) {
        int c  = tid + i * 256;
        int r  = c >> 4;
        int kc = (c & 15) << 3;
        uint4 v = *(const uint4*)(emb_bf + (size_t)(rg0 + r) * EDIM + kc);
        *(uint4*)(Als + r * LDK + kc) = v;
    }
    // stage B: 128 proxy rows x 128 k, tail-guarded
    #pragma unroll
    for (int i = 0; i < 8; ++i) {
        int c  = tid + i * 256;
        int n  = c >> 4;
        int kc = (c & 15) << 3;
        uint4 v = make_uint4(0u, 0u, 0u, 0u);
        if (c0 + n < NCLASS)
            v = *(const uint4*)(px_bf + (size_t)(c0 + n) * EDIM + kc);
        *(uint4*)(Bls + n * LDK + kc) = v;
    }
    __syncthreads();

    // wave (w>>1, w&1): 32-row x 64-col quadrant = 2x4 tiles of 16x16
    const int wr = (w >> 1) * 32;
    const int wc = (w & 1) * 64;
    const int fm = lane & 15;
    const int fq = lane >> 4;

    floatx4 acc[2][4];
    #pragma unroll
    for (int i = 0; i < 2; ++i)
        #pragma unroll
        for (int j = 0; j < 4; ++j)
            acc[i][j] = (floatx4){0.f, 0.f, 0.f, 0.f};

    #pragma unroll
    for (int kk = 0; kk < 4; ++kk) {
        const int kof = kk * 32 + fq * 8;
        short8 a[2], b[4];
        #pragma unroll
        for (int i = 0; i < 2; ++i)
            a[i] = *(const short8*)(Als + (wr + i * 16 + fm) * LDK + kof);
        #pragma unroll
        for (int j = 0; j < 4; ++j)
            b[j] = *(const short8*)(Bls + (wc + j * 16 + fm) * LDK + kof);
        #pragma unroll
        for (int i = 0; i < 2; ++i)
            #pragma unroll
            for (int j = 0; j < 4; ++j)
                acc[i][j] = __builtin_amdgcn_mfma_f32_16x16x32_bf16(
                    a[i], b[j], acc[i][j], 0, 0, 0);
    }

    __syncthreads();                       // all LDS reads done; reuse Als
    unsigned short* T = Als;               // 64 x LDK key16 tile (fits exactly)
    // C/D layout: col = lane&15, row = (lane>>4)*4 + reg
    #pragma unroll
    for (int j = 0; j < 4; ++j) {
        int col = wc + j * 16 + fm;
        #pragma unroll
        for (int i = 0; i < 2; ++i) {
            int rbase = wr + i * 16 + fq * 4;
            #pragma unroll
            for (int r = 0; r < 4; ++r)
                T[(rbase + r) * LDK + col] = (unsigned short)f2key16(acc[i][j][r]);
        }
    }
    __syncthreads();

    #pragma unroll
    for (int t = 0; t < 4; ++t) {
        int idx  = t * 256 + tid;          // 1024 groups of 8 keys
        int rowl = idx >> 4;
        int g    = idx & 15;
        int col  = c0 + g * 8;
        if (col < NCLASS) {                // 10000 % 8 == 0 -> group all-valid
            uint4 v = *(const uint4*)(T + rowl * LDK + g * 8);
            *(uint4*)(simk + (size_t)(rl0 + rowl) * NCLASS + col) = v;
        }
    }
}

// -------------------------------------------------------------- select ------
// One block per batch row, 2 global passes over the 20 KB key16 row (L2/L3
// hot), no key staging in LDS -> ~9.4 KB LDS -> 8 blocks/CU (wave-slot cap).
// Pass 1: 2048-bin (11-bit prefix) histogram. Register suffix-scan finds
// boundary bin b. Pass 2: exact exp-sum over bins > b, mean-fill in bin b.
__global__ __launch_bounds__(256) void select_kernel(
    const unsigned short* __restrict__ simk, const int* __restrict__ labels,
    const float* __restrict__ cw, float* __restrict__ out, int row0)
{
    __shared__ __align__(16) unsigned int hist[2048];   // 8192 B
    __shared__ __align__(16) unsigned int psum[256];    // 1024 B
    __shared__ float fred[8];
    __shared__ float s_pos;
    __shared__ unsigned int s_b, s_fill, s_cntb;

    const int tid   = threadIdx.x;
    const int lane  = tid & 63;
    const int w     = tid >> 6;
    const int rl    = blockIdx.x;
    const int label = labels[row0 + rl];
    const unsigned short* srow = simk + (size_t)rl * NCLASS;

    {
        uint4 z = make_uint4(0u, 0u, 0u, 0u);
        *(uint4*)&hist[tid * 8]     = z;
        *(uint4*)&hist[tid * 8 + 4] = z;
    }
    __syncthreads();

    // ---- pass 1: histogram from global ----
    for (int i = tid; i < NCLASS / 8; i += 256) {       // 1250 groups
        uint4 v = *(const uint4*)(srow + i * 8);
        unsigned int p[4] = {v.x, v.y, v.z, v.w};
        #pragma unroll
        for (int q = 0; q < 4; ++q) {
            atomicAdd(&hist[(p[q] & 0xFFFFu) >> 5], 1u);
            atomicAdd(&hist[(p[q] >> 16)     >> 5], 1u);
        }
    }
    __syncthreads();
    if (tid == 0) {
        unsigned int kl = srow[label];
        s_pos = key16val(kl);
        hist[kl >> 5] -= 1u;      // exclude positive from negatives
    }
    __syncthreads();

    // ---- suffix scan over 2048 bins, registers only ----
    uint4 h0 = *(const uint4*)&hist[tid * 8];
    uint4 h1 = *(const uint4*)&hist[tid * 8 + 4];
    unsigned int v[8] = {h0.x, h0.y, h0.z, h0.w, h1.x, h1.y, h1.z, h1.w};
    unsigned int sfx[8];
    sfx[7] = v[7];
    #pragma unroll
    for (int i = 6; i >= 0; --i) sfx[i] = sfx[i + 1] + v[i];
    psum[tid] = sfx[0];
    __syncthreads();
    if (w == 0) {
        uint4 g = *(const uint4*)&psum[lane * 4];
        unsigned int gs = g.x + g.y + g.z + g.w;
        unsigned int s = gs;
        #pragma unroll
        for (int off = 1; off < 64; off <<= 1) {
            unsigned int o = __shfl_down(s, off);
            if (lane + off < 64) s += o;
        }
        unsigned int above = s - gs;       // partials in strictly-higher lanes
        unsigned int a3 = above;
        unsigned int a2 = a3 + g.w;
        unsigned int a1 = a2 + g.z;
        unsigned int a0 = a1 + g.y;
        psum[lane * 4 + 0] = a0; psum[lane * 4 + 1] = a1;
        psum[lane * 4 + 2] = a2; psum[lane * 4 + 3] = a3;
    }
    __syncthreads();
    {
        unsigned int add = psum[tid];      // keys in bins of threads > tid
        #pragma unroll
        for (int i = 0; i < 8; ++i) {
            unsigned int cur = sfx[i] + add;
            unsigned int nxt = ((i < 7) ? sfx[i + 1] : 0u) + add;
            if (cur >= KSEL && nxt < KSEL) {   // exactly one (tid,i) matches
                s_b    = (unsigned int)(tid * 8 + i);
                s_fill = KSEL - nxt;
                s_cntb = v[i];
            }
        }
    }
    __syncthreads();

    // ---- pass 2: exp-sum, re-read row from global (L2/L3-hot) ----
    const unsigned int b = s_b;
    float sum = 0.f, bsum = 0.f;
    for (int i = tid; i < NCLASS / 8; i += 256) {
        uint4 pk = *(const uint4*)(srow + i * 8);
        unsigned int p[4] = {pk.x, pk.y, pk.z, pk.w};
        #pragma unroll
        for (int q = 0; q < 4; ++q) {
            unsigned int klo = p[q] & 0xFFFFu;
            unsigned int khi = p[q] >> 16;
            unsigned int blo = klo >> 5, bhi = khi >> 5;
            int idx = i * 8 + q * 2;
            if (blo >= b && idx != label) {
                float e = __expf(key16val(klo) - MLOG);
                if (blo > b) sum += e; else bsum += e;
            }
            if (bhi >= b && (idx + 1) != label) {
                float e = __expf(key16val(khi) - MLOG);
                if (bhi > b) sum += e; else bsum += e;
            }
        }
    }
    #pragma unroll
    for (int off = 32; off; off >>= 1) {
        sum  += __shfl_xor(sum, off);
        bsum += __shfl_xor(bsum, off);
    }
    if (lane == 0) { fred[w] = sum; fred[4 + w] = bsum; }
    __syncthreads();

    if (tid == 0) {
        float S  = fred[0] + fred[1] + fred[2] + fred[3];
        float Bs = fred[4] + fred[5] + fred[6] + fred[7];
        float ep = __expf(s_pos - MLOG);
        float denom = S + Bs * ((float)s_fill / (float)s_cntb) + ep;
        float p  = ep / denom;
        float ce = -logf(p + 1e-8f);
        float focal = 0.25f * (1.0f - p) * (1.0f - p) * ce;
        atomicAdd(out, focal * cw[label] * (1.0f / (float)BATCH));
    }
}

// ------------------------------------------------------------ launcher ------
extern "C" void kernel_launch(void* const* d_in, const int* in_sizes, int n_in,
                              void* d_out, int out_size, void* d_ws, size_t ws_size,
                              hipStream_t stream) {
    const float* emb    = (const float*)d_in[0];   // 4096 x 128
    const int*   labels = (const int*)d_in[1];     // 4096
    const float* cw     = (const float*)d_in[2];   // 10000
    const float* px     = (const float*)d_in[3];   // 10000 x 128
    float* out = (float*)d_out;
    char*  wsc = (char*)d_ws;

    unsigned short* px_bf  = (unsigned short*)wsc;               // 10000*128 bf16
    unsigned short* emb_bf = (unsigned short*)(wsc + 2560000);   // 4096*128 bf16
    unsigned short* simk   = (unsigned short*)(wsc + 3608576);   // chunk x 10000 key16

    size_t fixed = 3608576;
    size_t avail = (ws_size > fixed) ? (ws_size - fixed) : 0;
    long long cap = (long long)(avail / ((size_t)NCLASS * 2));
    int chunk = (int)((cap / 128) * 128);
    if (chunk > BATCH) chunk = BATCH;
    if (chunk < 128) chunk = 128;

    prep_kernel<<<3524, 256, 0, stream>>>(emb, px, px_bf, emb_bf, out);

    for (int r0 = 0; r0 < BATCH; r0 += chunk) {
        int rows = (BATCH - r0 < chunk) ? (BATCH - r0) : chunk;
        dim3 ggrid((NCLASS + 127) / 128, rows / 64);
        gemm_kernel<<<ggrid, 256, 0, stream>>>(emb_bf, px_bf, simk, r0);
        select_kernel<<<rows, 256, 0, stream>>>(simk, labels, cw, out, r0);
    }
}